// Round 1
// baseline (443.242 us; speedup 1.0000x reference)
//
#include <hip/hip_runtime.h>

// y[b,t,:] = x[b,t+1,:] - x[b,t,:]  for t < L-1
// y[b,L-1,:] = x[b,L-1,:] - x[b,L-2,:]
// B=16, L=8192, F=512, fp32. Flat elementwise with float4 vectorization.

#define B_   16
#define L_   8192
#define F_   512
#define F4_  (F_ / 4)          // 128 float4 per step
#define LF4_ (L_ * F4_)        // float4 per batch = 2^20

__global__ __launch_bounds__(256) void diff1d_kernel(
    const float4* __restrict__ x, float4* __restrict__ y, int n4) {
    int i = blockIdx.x * blockDim.x + threadIdx.x;
    if (i >= n4) return;

    // t = (i % LF4_) / F4_  — powers of two, so mask + shift
    int t = (i & (LF4_ - 1)) >> 7;   // F4_ = 128 = 2^7

    float4 a, b;
    if (t == L_ - 1) {
        a = x[i];
        b = x[i - F4_];
    } else {
        a = x[i + F4_];
        b = x[i];
    }
    y[i] = make_float4(a.x - b.x, a.y - b.y, a.z - b.z, a.w - b.w);
}

extern "C" void kernel_launch(void* const* d_in, const int* in_sizes, int n_in,
                              void* d_out, int out_size, void* d_ws, size_t ws_size,
                              hipStream_t stream) {
    const float4* x = (const float4*)d_in[0];
    float4* y = (float4*)d_out;
    int n4 = in_sizes[0] / 4;   // 16*8192*512/4 = 16,777,216
    int block = 256;
    int grid = (n4 + block - 1) / block;  // 65536
    diff1d_kernel<<<grid, block, 0, stream>>>(x, y, n4);
}